// Round 11
// baseline (688.695 us; speedup 1.0000x reference)
//
#include <hip/hip_runtime.h>
#include <hip/hip_bf16.h>
#include <math.h>

typedef unsigned int  uint;
typedef unsigned short ushort;

// Problem constants
#define DD    256      // embedding dim
#define KK    2048     // num codewords
#define HW    1024     // H*W
#define NN    32768    // rows
#define NUMEL 8388608  // total elements
#define STRIDEB (DD*HW)
#define NQBLK 4096     // quant blocks

// Workspace layout (bytes) — total 2,629,760 (< 2,670,720 proven in R1-R9)
#define WS_H2P    0         // 16 x 2048 f32 h2 partials (128 KB)
#define WS_COUNTS 131072    // 2048 i32
#define WS_DONE   139264    // 1 i32 (+pad)
#define WS_EBF    139392    // emb frag-ordered bf16 hi/lo: 2 MB
#define WS_PV     2236544   // 65536 f32 partial best value (N x 2 halves)
#define WS_PI     2498688   // 65536 u16 partial best index (128 KB)
// bpart aliases h2p: h2p is dead after argmin; quant runs after (stream order).
#define WS_BPART  WS_H2P    // 4096 f32

// Output layout (floats): quantized_st | loss | perplexity | indices(as float)
#define OUT_LOSS  8388608
#define OUT_PPL   8388609
#define OUT_IDX   8388610

typedef __attribute__((ext_vector_type(8))) short  short8;    // 8 bf16 (4 VGPR)
typedef __attribute__((ext_vector_type(8))) ushort ushort8;   // 8 u16
typedef __attribute__((ext_vector_type(4))) float  float4v;   // 4 fp32 acc

typedef __attribute__((address_space(1))) uint guint;  // global
typedef __attribute__((address_space(3))) uint luint;  // LDS

__device__ __forceinline__ ushort f2bf(float f) {   // RNE fp32->bf16 bits
    uint u = __float_as_uint(f);
    return (ushort)((u + 0x7FFFu + ((u >> 16) & 1u)) >> 16);
}

// --------------------------------------------------------------------------
// Kernel 1: reorder emb (D,K) fp32 into MFMA-B-fragment-major bf16 hi/lo.
// R10 tail fix (dispatch-count): h2 becomes 16 per-dg2 PARTIAL slabs
// (plain stores — no atomics, no memset dispatch); argmin sums them.
// Block 0 zeroes counts + done (their consumers are later dispatches).
__global__ __launch_bounds__(256) void prep_emb(const float* __restrict__ emb,
                                                ushort* __restrict__ ebf,
                                                float* __restrict__ h2p,
                                                int* __restrict__ counts,
                                                int* __restrict__ done) {
    int g   = blockIdx.x * 256 + threadIdx.x;   // [0, 32768)
    int k   = g & (KK - 1);
    int dg2 = g >> 11;          // 0..15 (two dg groups per thread)
    int ct  = k >> 4;
    float p2 = 0.f;
#pragma unroll
    for (int h = 0; h < 2; ++h) {
        int dg = dg2 * 2 + h;
        int d0 = dg * 8;
        int s    = dg >> 2;
        int quad = dg & 3;
        int l    = quad * 16 + (k & 15);
        union { ushort us[8]; uint4 v; } hu, lu;
#pragma unroll
        for (int j = 0; j < 8; ++j) {
            float v = emb[(size_t)(d0 + j) * KK + k];
            p2 += v * v;
            ushort hb = f2bf(v);
            float  hf = __uint_as_float(((uint)hb) << 16);
            hu.us[j] = hb;
            lu.us[j] = f2bf(v - hf);
        }
        size_t hi_off = (size_t)(((ct * 8 + s) * 2 + 0) * 64 + l) * 8;
        size_t lo_off = (size_t)(((ct * 8 + s) * 2 + 1) * 64 + l) * 8;
        *(uint4*)(ebf + hi_off) = hu.v;
        *(uint4*)(ebf + lo_off) = lu.v;
    }
    h2p[dg2 * 2048 + k] = 0.5f * p2;
    if (blockIdx.x == 0) {
        for (int i = threadIdx.x; i < KK; i += 256) counts[i] = 0;
        if (threadIdx.x == 0) *done = 0;
    }
}

// --------------------------------------------------------------------------
// Kernel 2: split-bf16 MFMA distance + per-row argmin over a column half.
// EXACT R9 structure (verified 108.0 us; R10's xs2 add cost +4 us — reverted.
// Ledger: 7 schedule variants all 37-40% MfmaUtil; this is the structure's
// ceiling, do not re-iterate without asm evidence). Changes vs R9: sH2 is
// summed from 16 h2p partial slabs (L2-resident, coalesced); pi is ushort.
// pv = raw bv: merge compares are invariant to the per-row xs2 shift.
__global__ __launch_bounds__(256, 2) void argmin_mfma(
    const float*  __restrict__ x,
    const ushort* __restrict__ ebf,
    const float*  __restrict__ h2p,
    float*  __restrict__ pv,
    ushort* __restrict__ pi)
{
    __shared__ ushort sB[2][8192];   // 2 x 16 KB tile double-buffer
    __shared__ float  sH2[1024];     // 4 KB: h2 for this column half

    const int tid  = threadIdx.x;
    const int w    = tid >> 6;
    const int lane = tid & 63;
    const int m    = lane & 15;
    const int quad = lane >> 4;

    const int rb = blockIdx.x >> 1;
    const int ch = blockIdx.x & 1;
    const int n0 = rb * 128 + w * 32;          // wave's first row
    const int b  = n0 >> 10;
    const int hwb = n0 & 1023;
    const float* xb = x + (size_t)b * STRIDEB;
    const int cbase = ch * 1024;
    const int ctg0  = cbase >> 4;

    auto stage = [&](ushort* dst, int ctg) {
        const char* gs = (const char*)(ebf + (size_t)ctg * 8192) + tid * 16;
        char*       ls = (char*)dst + tid * 16;
#pragma unroll
        for (int i = 0; i < 4; ++i)
            __builtin_amdgcn_global_load_lds((guint*)(gs + i * 4096),
                                             (luint*)(ls + i * 4096),
                                             16, 0, 0);
    };

    stage(sB[0], ctg0);
    {   // sum the 16 h2 partial slabs (one float4/thread per slab)
        float4 a = {0.f, 0.f, 0.f, 0.f};
#pragma unroll
        for (int d = 0; d < 16; ++d) {
            float4 v = ((const float4*)(h2p + d * 2048 + cbase))[tid];
            a.x += v.x; a.y += v.y; a.z += v.z; a.w += v.w;
        }
        ((float4*)sH2)[tid] = a;
    }

    // A fragments in registers: 2 strips x 8 slices x (hi,lo).
    short8 xh[2][8], xl[2][8];
#pragma unroll
    for (int st = 0; st < 2; ++st) {
        const int hw = hwb + st * 16 + m;
#pragma unroll
        for (int s = 0; s < 8; ++s) {
            const float* p = xb + (size_t)(s * 32 + quad * 8) * HW + hw;
            short8 hh, ll;
#pragma unroll
            for (int j = 0; j < 8; ++j) {
                float v = p[(size_t)j * HW];
                v = fminf(fmaxf(v, -10.f), 10.f);
                ushort hb = f2bf(v);
                float  hf = __uint_as_float(((uint)hb) << 16);
                hh[j] = (short)hb;
                ll[j] = (short)f2bf(v - hf);
            }
            xh[st][s] = hh;
            xl[st][s] = ll;
        }
    }

    float bv[2][4] = {{1e30f,1e30f,1e30f,1e30f},{1e30f,1e30f,1e30f,1e30f}};
    int   bi[2][4] = {{0,0,0,0},{0,0,0,0}};

    auto compute_tile = [&](const ushort* sbc, int ct) {
        float4v ahh0 = {0,0,0,0}, ahl0 = {0,0,0,0}, alh0 = {0,0,0,0};
        float4v ahh1 = {0,0,0,0}, ahl1 = {0,0,0,0}, alh1 = {0,0,0,0};
#pragma unroll
        for (int s = 0; s < 8; ++s) {
            short8 eh = *(const short8*)&sbc[(s * 2 + 0) * 512 + lane * 8];
            short8 el = *(const short8*)&sbc[(s * 2 + 1) * 512 + lane * 8];
            alh0 = __builtin_amdgcn_mfma_f32_16x16x32_bf16(xl[0][s], eh, alh0, 0, 0, 0);
            ahl0 = __builtin_amdgcn_mfma_f32_16x16x32_bf16(xh[0][s], el, ahl0, 0, 0, 0);
            ahh0 = __builtin_amdgcn_mfma_f32_16x16x32_bf16(xh[0][s], eh, ahh0, 0, 0, 0);
            alh1 = __builtin_amdgcn_mfma_f32_16x16x32_bf16(xl[1][s], eh, alh1, 0, 0, 0);
            ahl1 = __builtin_amdgcn_mfma_f32_16x16x32_bf16(xh[1][s], el, ahl1, 0, 0, 0);
            ahh1 = __builtin_amdgcn_mfma_f32_16x16x32_bf16(xh[1][s], eh, ahh1, 0, 0, 0);
        }
        const int c  = cbase + ct * 16 + m;
        const float hv = sH2[ct * 16 + m];
#pragma unroll
        for (int i = 0; i < 4; ++i) {
            float s0 = hv - (ahh0[i] + (ahl0[i] + alh0[i]));
            float s1 = hv - (ahh1[i] + (ahl1[i] + alh1[i]));
            if (s0 < bv[0][i]) { bv[0][i] = s0; bi[0][i] = c; }
            if (s1 < bv[1][i]) { bv[1][i] = s1; bi[1][i] = c; }
        }
    };

    __syncthreads();   // drains tile-0 DMA (vmcnt) + sH2 write (lgkmcnt)

    for (int ct = 0; ct < 64; ct += 2) {
        stage(sB[1], ctg0 + ct + 1);
        compute_tile(sB[0], ct);
        __syncthreads();
        stage(sB[0], (ct + 2 < 64) ? (ctg0 + ct + 2) : ctg0);
        compute_tile(sB[1], ct + 1);
        __syncthreads();
    }

#pragma unroll
    for (int st = 0; st < 2; ++st) {
#pragma unroll
        for (int i = 0; i < 4; ++i) {
            float v  = bv[st][i];
            int   ix = bi[st][i];
#pragma unroll
            for (int msk = 8; msk >= 1; msk >>= 1) {
                float ov = __shfl_xor(v, msk, 64);
                int   oi = __shfl_xor(ix, msk, 64);
                if (ov < v || (ov == v && oi < ix)) { v = ov; ix = oi; }
            }
            if (m == 0) {
                int n = n0 + st * 16 + quad * 4 + i;
                pv[n * 2 + ch] = v;
                pi[n * 2 + ch] = (ushort)min(max(ix, 0), KK - 1);
            }
        }
    }
}

// --------------------------------------------------------------------------
// Kernel 3: merge + gather + outq + histogram + MSE + FUSED finalize.
// Block = (b, d-pair); merge once/row; gather from LDS; MSE vs x; bpart
// plain store (NEVER same-address atomics — R3 lesson). Last block (done
// counter, threadfence release/acquire = the documented XCD-safe pattern)
// reduces bpart + counts-entropy and writes loss/ppl — finalize dispatch
// deleted (R10 post-mortem: ~16 us per dispatch boundary).
__global__ __launch_bounds__(256) void quant_kernel(
    const float*  __restrict__ x,
    const float*  __restrict__ emb,
    const float*  __restrict__ pv,
    const ushort* __restrict__ pi,
    int*   __restrict__ counts,
    float* __restrict__ out,      // base: outq | loss | ppl | idx
    float* __restrict__ bpart,
    int*   __restrict__ done)
{
    __shared__ float sE[4096];    // emb rows d0, d0+1 (16 KB)
    __shared__ int   sIdx[1024];  // merged index per row of this b
    __shared__ float red[4], redl[4];
    __shared__ int   sLast;

    const int tid  = threadIdx.x;
    const int bidx = blockIdx.x;
    const int b    = bidx >> 7;        // 0..31
    const int dp   = bidx & 127;       // d-pair 0..127
    const int d0   = dp * 2;
    const int nbase = b * HW;

    // Stage 2 contiguous emb rows: 4096 floats, 4 x float4 per thread.
    {
        const float4* src = (const float4*)(emb + (size_t)d0 * KK);
        float4* dst = (float4*)sE;
#pragma unroll
        for (int i = 0; i < 4; ++i) dst[tid + i * 256] = src[tid + i * 256];
    }
    // Merge the two column halves for 4 rows/thread (strict <, half-0 on
    // ties — identical semantics to R9/R10).
    {
        const int n = nbase + tid * 4;
        const float4* pv4 = (const float4*)(pv + (size_t)n * 2);
        float4 pva = pv4[0], pvb = pv4[1];
        ushort8 pp = *(const ushort8*)(pi + (size_t)n * 2);
        int i0 = (pva.y < pva.x) ? (int)pp[1] : (int)pp[0];
        int i1 = (pva.w < pva.z) ? (int)pp[3] : (int)pp[2];
        int i2 = (pvb.y < pvb.x) ? (int)pp[5] : (int)pp[4];
        int i3 = (pvb.w < pvb.z) ? (int)pp[7] : (int)pp[6];
        i0 = min(i0, KK - 1); i1 = min(i1, KK - 1);
        i2 = min(i2, KK - 1); i3 = min(i3, KK - 1);
        sIdx[tid * 4 + 0] = i0; sIdx[tid * 4 + 1] = i1;
        sIdx[tid * 4 + 2] = i2; sIdx[tid * 4 + 3] = i3;
        if (d0 == 0) {   // one writer per n: emit index + histogram
            float4 ixf = { (float)i0, (float)i1, (float)i2, (float)i3 };
            *(float4*)(out + OUT_IDX + n) = ixf;
            atomicAdd(&counts[i0], 1);
            atomicAdd(&counts[i1], 1);
            atomicAdd(&counts[i2], 1);
            atomicAdd(&counts[i3], 1);
        }
    }
    __syncthreads();

    // Gather 8 elements (fixed d, consecutive hw) from LDS; MSE vs x.
    float s;
    {
        const int e   = tid * 8;          // 0..2047 within block span
        const int dl  = e >> 10;          // 0 or 1
        const int hw0 = e & 1023;
        const float* row = sE + dl * 2048;
        float q[8];
#pragma unroll
        for (int j = 0; j < 8; ++j) q[j] = row[sIdx[hw0 + j]];
        const size_t go = (size_t)bidx * 2048 + e;
        const float4 xv0 = *(const float4*)(x + go);
        const float4 xv1 = *(const float4*)(x + go + 4);
        float4 q0 = { q[0], q[1], q[2], q[3] };
        float4 q1 = { q[4], q[5], q[6], q[7] };
        *(float4*)(out + go)     = q0;
        *(float4*)(out + go + 4) = q1;
        float a0 = q0.x - xv0.x, a1 = q0.y - xv0.y, a2 = q0.z - xv0.z, a3 = q0.w - xv0.w;
        float a4 = q1.x - xv1.x, a5 = q1.y - xv1.y, a6 = q1.z - xv1.z, a7 = q1.w - xv1.w;
        s = a0*a0 + a1*a1 + a2*a2 + a3*a3 + a4*a4 + a5*a5 + a6*a6 + a7*a7;
    }
#pragma unroll
    for (int off = 32; off > 0; off >>= 1) s += __shfl_down(s, off, 64);
    if ((tid & 63) == 0) red[tid >> 6] = s;
    __syncthreads();
    if (tid == 0) bpart[bidx] = red[0] + red[1] + red[2] + red[3];

    // Completion signal: release fence, then count; last block finalizes.
    __threadfence();
    __syncthreads();
    if (tid == 0) { int prev = atomicAdd(done, 1); sLast = (prev == NQBLK - 1); }
    __syncthreads();
    if (sLast) {
        __threadfence();   // acquire: see all blocks' bpart + counts
        float sp = 0.f;
        for (int k = tid; k < KK; k += 256) {
            float p = (float)counts[k] * (1.0f / (float)NN);
            sp += p * logf(p + 1e-10f);
        }
        float ls = 0.f;
        for (int i = tid; i < NQBLK; i += 256) ls += bpart[i];
#pragma unroll
        for (int off = 32; off > 0; off >>= 1) {
            sp += __shfl_down(sp, off, 64);
            ls += __shfl_down(ls, off, 64);
        }
        if ((tid & 63) == 0) { red[tid >> 6] = sp; redl[tid >> 6] = ls; }
        __syncthreads();
        if (tid == 0) {
            float tot  = red[0] + red[1] + red[2] + red[3];
            float lsum = redl[0] + redl[1] + redl[2] + redl[3];
            out[OUT_PPL]  = expf(-tot);
            out[OUT_LOSS] = lsum * 1.25f / (float)NUMEL;
        }
    }
}

// --------------------------------------------------------------------------
extern "C" void kernel_launch(void* const* d_in, const int* in_sizes, int n_in,
                              void* d_out, int out_size, void* d_ws, size_t ws_size,
                              hipStream_t stream) {
    const float* x   = (const float*)d_in[0];
    const float* emb = (const float*)d_in[1];
    float* out = (float*)d_out;
    char*  ws  = (char*)d_ws;

    float*  h2p    = (float*)(ws + WS_H2P);
    int*    counts = (int*)(ws + WS_COUNTS);
    int*    done   = (int*)(ws + WS_DONE);
    ushort* ebf    = (ushort*)(ws + WS_EBF);
    float*  pv     = (float*)(ws + WS_PV);
    ushort* pi     = (ushort*)(ws + WS_PI);
    float*  bpart  = (float*)(ws + WS_BPART);   // aliases h2p (dead after argmin)

    prep_emb<<<128, 256, 0, stream>>>(emb, ebf, h2p, counts, done);
    argmin_mfma<<<512, 256, 0, stream>>>(x, ebf, h2p, pv, pi);
    quant_kernel<<<NQBLK, 256, 0, stream>>>(x, emb, pv, pi, counts, out, bpart, done);
}

// Round 12
// 196.668 us; speedup vs baseline: 3.5018x; 3.5018x over previous
//
#include <hip/hip_runtime.h>
#include <hip/hip_bf16.h>
#include <math.h>

typedef unsigned int  uint;
typedef unsigned short ushort;

// Problem constants
#define DD    256      // embedding dim
#define KK    2048     // num codewords
#define HW    1024     // H*W
#define NN    32768    // rows
#define NUMEL 8388608  // total elements
#define STRIDEB (DD*HW)
#define NQBLK 4096     // quant blocks

// Workspace layout (bytes) — total 2,629,760
#define WS_H2P    0         // 16 x 2048 f32 h2 partials (128 KB)
#define WS_COUNTS 131072    // 2048 i32
#define WS_EBF    139392    // emb frag-ordered bf16 hi/lo: 2 MB
#define WS_PV     2236544   // 65536 f32 partial best value (N x 2 halves)
#define WS_PI     2498688   // 65536 u16 partial best index (128 KB)
// bpart aliases h2p: h2p is dead after argmin; quant runs after (stream order).
#define WS_BPART  WS_H2P    // 4096 f32

// Output layout (floats): quantized_st | loss | perplexity | indices(as float)
#define OUT_LOSS  8388608
#define OUT_PPL   8388609
#define OUT_IDX   8388610

typedef __attribute__((ext_vector_type(8))) short  short8;    // 8 bf16 (4 VGPR)
typedef __attribute__((ext_vector_type(8))) ushort ushort8;   // 8 u16
typedef __attribute__((ext_vector_type(4))) float  float4v;   // 4 fp32 acc

typedef __attribute__((address_space(1))) uint guint;  // global
typedef __attribute__((address_space(3))) uint luint;  // LDS

__device__ __forceinline__ ushort f2bf(float f) {   // RNE fp32->bf16 bits
    uint u = __float_as_uint(f);
    return (ushort)((u + 0x7FFFu + ((u >> 16) & 1u)) >> 16);
}

// --------------------------------------------------------------------------
// Kernel 1: reorder emb (D,K) fp32 into MFMA-B-fragment-major bf16 hi/lo.
// h2 kept as 16 partial slabs (plain stores, no memset dispatch needed);
// argmin sums them. Block 0 zeroes counts (consumer is 2 dispatches later).
// R11 LESSON (never repeat): fusing finalize into quant via per-block
// __threadfence() = device-scope fence = L2 writeback on non-coherent-XCD
// gfx950 -> 4096 fences serialized 71 MB of dirty lines at 114 GB/s =
// 620 us (VALUBusy 0.4%). Discrete dispatches cost ~16 us each; a
// per-block device fence on a bulk-write kernel costs 30x that.
__global__ __launch_bounds__(256) void prep_emb(const float* __restrict__ emb,
                                                ushort* __restrict__ ebf,
                                                float* __restrict__ h2p,
                                                int* __restrict__ counts) {
    int g   = blockIdx.x * 256 + threadIdx.x;   // [0, 32768)
    int k   = g & (KK - 1);
    int dg2 = g >> 11;          // 0..15 (two dg groups per thread)
    int ct  = k >> 4;
    float p2 = 0.f;
#pragma unroll
    for (int h = 0; h < 2; ++h) {
        int dg = dg2 * 2 + h;
        int d0 = dg * 8;
        int s    = dg >> 2;
        int quad = dg & 3;
        int l    = quad * 16 + (k & 15);
        union { ushort us[8]; uint4 v; } hu, lu;
#pragma unroll
        for (int j = 0; j < 8; ++j) {
            float v = emb[(size_t)(d0 + j) * KK + k];
            p2 += v * v;
            ushort hb = f2bf(v);
            float  hf = __uint_as_float(((uint)hb) << 16);
            hu.us[j] = hb;
            lu.us[j] = f2bf(v - hf);
        }
        size_t hi_off = (size_t)(((ct * 8 + s) * 2 + 0) * 64 + l) * 8;
        size_t lo_off = (size_t)(((ct * 8 + s) * 2 + 1) * 64 + l) * 8;
        *(uint4*)(ebf + hi_off) = hu.v;
        *(uint4*)(ebf + lo_off) = lu.v;
    }
    h2p[dg2 * 2048 + k] = 0.5f * p2;
    if (blockIdx.x == 0) {
        for (int i = threadIdx.x; i < KK; i += 256) counts[i] = 0;
    }
}

// --------------------------------------------------------------------------
// Kernel 2: split-bf16 MFMA distance + per-row argmin over a column half.
// EXACT R9 structure (verified 108.0 us, best of all measured variants —
// ledger: 7 schedule rewrites all pinned at MfmaUtil 37-40%; R10's xs2
// add cost +4 us and was reverted. Do not touch without asm evidence).
// sH2 summed from 16 h2p slabs (L2-resident, coalesced); pi is ushort.
__global__ __launch_bounds__(256, 2) void argmin_mfma(
    const float*  __restrict__ x,
    const ushort* __restrict__ ebf,
    const float*  __restrict__ h2p,
    float*  __restrict__ pv,
    ushort* __restrict__ pi)
{
    __shared__ ushort sB[2][8192];   // 2 x 16 KB tile double-buffer
    __shared__ float  sH2[1024];     // 4 KB: h2 for this column half

    const int tid  = threadIdx.x;
    const int w    = tid >> 6;
    const int lane = tid & 63;
    const int m    = lane & 15;
    const int quad = lane >> 4;

    const int rb = blockIdx.x >> 1;
    const int ch = blockIdx.x & 1;
    const int n0 = rb * 128 + w * 32;          // wave's first row
    const int b  = n0 >> 10;
    const int hwb = n0 & 1023;
    const float* xb = x + (size_t)b * STRIDEB;
    const int cbase = ch * 1024;
    const int ctg0  = cbase >> 4;

    auto stage = [&](ushort* dst, int ctg) {
        const char* gs = (const char*)(ebf + (size_t)ctg * 8192) + tid * 16;
        char*       ls = (char*)dst + tid * 16;
#pragma unroll
        for (int i = 0; i < 4; ++i)
            __builtin_amdgcn_global_load_lds((guint*)(gs + i * 4096),
                                             (luint*)(ls + i * 4096),
                                             16, 0, 0);
    };

    stage(sB[0], ctg0);
    {   // sum the 16 h2 partial slabs (one float4/thread per slab)
        float4 a = {0.f, 0.f, 0.f, 0.f};
#pragma unroll
        for (int d = 0; d < 16; ++d) {
            float4 v = ((const float4*)(h2p + d * 2048 + cbase))[tid];
            a.x += v.x; a.y += v.y; a.z += v.z; a.w += v.w;
        }
        ((float4*)sH2)[tid] = a;
    }

    // A fragments in registers: 2 strips x 8 slices x (hi,lo).
    short8 xh[2][8], xl[2][8];
#pragma unroll
    for (int st = 0; st < 2; ++st) {
        const int hw = hwb + st * 16 + m;
#pragma unroll
        for (int s = 0; s < 8; ++s) {
            const float* p = xb + (size_t)(s * 32 + quad * 8) * HW + hw;
            short8 hh, ll;
#pragma unroll
            for (int j = 0; j < 8; ++j) {
                float v = p[(size_t)j * HW];
                v = fminf(fmaxf(v, -10.f), 10.f);
                ushort hb = f2bf(v);
                float  hf = __uint_as_float(((uint)hb) << 16);
                hh[j] = (short)hb;
                ll[j] = (short)f2bf(v - hf);
            }
            xh[st][s] = hh;
            xl[st][s] = ll;
        }
    }

    float bv[2][4] = {{1e30f,1e30f,1e30f,1e30f},{1e30f,1e30f,1e30f,1e30f}};
    int   bi[2][4] = {{0,0,0,0},{0,0,0,0}};

    auto compute_tile = [&](const ushort* sbc, int ct) {
        float4v ahh0 = {0,0,0,0}, ahl0 = {0,0,0,0}, alh0 = {0,0,0,0};
        float4v ahh1 = {0,0,0,0}, ahl1 = {0,0,0,0}, alh1 = {0,0,0,0};
#pragma unroll
        for (int s = 0; s < 8; ++s) {
            short8 eh = *(const short8*)&sbc[(s * 2 + 0) * 512 + lane * 8];
            short8 el = *(const short8*)&sbc[(s * 2 + 1) * 512 + lane * 8];
            alh0 = __builtin_amdgcn_mfma_f32_16x16x32_bf16(xl[0][s], eh, alh0, 0, 0, 0);
            ahl0 = __builtin_amdgcn_mfma_f32_16x16x32_bf16(xh[0][s], el, ahl0, 0, 0, 0);
            ahh0 = __builtin_amdgcn_mfma_f32_16x16x32_bf16(xh[0][s], eh, ahh0, 0, 0, 0);
            alh1 = __builtin_amdgcn_mfma_f32_16x16x32_bf16(xl[1][s], eh, alh1, 0, 0, 0);
            ahl1 = __builtin_amdgcn_mfma_f32_16x16x32_bf16(xh[1][s], el, ahl1, 0, 0, 0);
            ahh1 = __builtin_amdgcn_mfma_f32_16x16x32_bf16(xh[1][s], eh, ahh1, 0, 0, 0);
        }
        const int c  = cbase + ct * 16 + m;
        const float hv = sH2[ct * 16 + m];
#pragma unroll
        for (int i = 0; i < 4; ++i) {
            float s0 = hv - (ahh0[i] + (ahl0[i] + alh0[i]));
            float s1 = hv - (ahh1[i] + (ahl1[i] + alh1[i]));
            if (s0 < bv[0][i]) { bv[0][i] = s0; bi[0][i] = c; }
            if (s1 < bv[1][i]) { bv[1][i] = s1; bi[1][i] = c; }
        }
    };

    __syncthreads();   // drains tile-0 DMA (vmcnt) + sH2 write (lgkmcnt)

    for (int ct = 0; ct < 64; ct += 2) {
        stage(sB[1], ctg0 + ct + 1);
        compute_tile(sB[0], ct);
        __syncthreads();
        stage(sB[0], (ct + 2 < 64) ? (ctg0 + ct + 2) : ctg0);
        compute_tile(sB[1], ct + 1);
        __syncthreads();
    }

#pragma unroll
    for (int st = 0; st < 2; ++st) {
#pragma unroll
        for (int i = 0; i < 4; ++i) {
            float v  = bv[st][i];
            int   ix = bi[st][i];
#pragma unroll
            for (int msk = 8; msk >= 1; msk >>= 1) {
                float ov = __shfl_xor(v, msk, 64);
                int   oi = __shfl_xor(ix, msk, 64);
                if (ov < v || (ov == v && oi < ix)) { v = ov; ix = oi; }
            }
            if (m == 0) {
                int n = n0 + st * 16 + quad * 4 + i;
                pv[n * 2 + ch] = v;
                pi[n * 2 + ch] = (ushort)min(max(ix, 0), KK - 1);
            }
        }
    }
}

// --------------------------------------------------------------------------
// Kernel 3: merge + gather + outq + histogram + MSE partials. NO fence, NO
// done-counter (R11 lesson). bpart is a plain per-block store (never
// same-address atomics — R3 lesson). Block = (b, d-pair): stage 2 emb rows
// (16 KB) coalesced; merge its 1024 rows once; gather from LDS.
__global__ __launch_bounds__(256) void quant_kernel(
    const float*  __restrict__ x,
    const float*  __restrict__ emb,
    const float*  __restrict__ pv,
    const ushort* __restrict__ pi,
    int*   __restrict__ counts,
    float* __restrict__ out,      // base: outq | loss | ppl | idx
    float* __restrict__ bpart)
{
    __shared__ float sE[4096];    // emb rows d0, d0+1 (16 KB)
    __shared__ int   sIdx[1024];  // merged index per row of this b
    __shared__ float red[4];

    const int tid  = threadIdx.x;
    const int bidx = blockIdx.x;
    const int b    = bidx >> 7;        // 0..31
    const int dp   = bidx & 127;       // d-pair 0..127
    const int d0   = dp * 2;
    const int nbase = b * HW;

    {   // Stage 2 contiguous emb rows: 4096 floats, 4 x float4 per thread.
        const float4* src = (const float4*)(emb + (size_t)d0 * KK);
        float4* dst = (float4*)sE;
#pragma unroll
        for (int i = 0; i < 4; ++i) dst[tid + i * 256] = src[tid + i * 256];
    }
    {   // Merge the two halves for 4 rows/thread (strict <, half-0 on ties).
        const int n = nbase + tid * 4;
        const float4* pv4 = (const float4*)(pv + (size_t)n * 2);
        float4 pva = pv4[0], pvb = pv4[1];
        ushort8 pp = *(const ushort8*)(pi + (size_t)n * 2);
        int i0 = (pva.y < pva.x) ? (int)pp[1] : (int)pp[0];
        int i1 = (pva.w < pva.z) ? (int)pp[3] : (int)pp[2];
        int i2 = (pvb.y < pvb.x) ? (int)pp[5] : (int)pp[4];
        int i3 = (pvb.w < pvb.z) ? (int)pp[7] : (int)pp[6];
        i0 = min(i0, KK - 1); i1 = min(i1, KK - 1);
        i2 = min(i2, KK - 1); i3 = min(i3, KK - 1);
        sIdx[tid * 4 + 0] = i0; sIdx[tid * 4 + 1] = i1;
        sIdx[tid * 4 + 2] = i2; sIdx[tid * 4 + 3] = i3;
        if (d0 == 0) {   // one writer per n: emit index + histogram
            float4 ixf = { (float)i0, (float)i1, (float)i2, (float)i3 };
            *(float4*)(out + OUT_IDX + n) = ixf;
            atomicAdd(&counts[i0], 1);
            atomicAdd(&counts[i1], 1);
            atomicAdd(&counts[i2], 1);
            atomicAdd(&counts[i3], 1);
        }
    }
    __syncthreads();

    // Gather 8 elements (fixed d, consecutive hw) from LDS; MSE vs x.
    float s;
    {
        const int e   = tid * 8;          // 0..2047 within block span
        const int dl  = e >> 10;          // 0 or 1
        const int hw0 = e & 1023;
        const float* row = sE + dl * 2048;
        float q[8];
#pragma unroll
        for (int j = 0; j < 8; ++j) q[j] = row[sIdx[hw0 + j]];
        const size_t go = (size_t)bidx * 2048 + e;
        const float4 xv0 = *(const float4*)(x + go);
        const float4 xv1 = *(const float4*)(x + go + 4);
        float4 q0 = { q[0], q[1], q[2], q[3] };
        float4 q1 = { q[4], q[5], q[6], q[7] };
        *(float4*)(out + go)     = q0;
        *(float4*)(out + go + 4) = q1;
        float a0 = q0.x - xv0.x, a1 = q0.y - xv0.y, a2 = q0.z - xv0.z, a3 = q0.w - xv0.w;
        float a4 = q1.x - xv1.x, a5 = q1.y - xv1.y, a6 = q1.z - xv1.z, a7 = q1.w - xv1.w;
        s = a0*a0 + a1*a1 + a2*a2 + a3*a3 + a4*a4 + a5*a5 + a6*a6 + a7*a7;
    }
#pragma unroll
    for (int off = 32; off > 0; off >>= 1) s += __shfl_down(s, off, 64);
    if ((tid & 63) == 0) red[tid >> 6] = s;
    __syncthreads();
    if (tid == 0) bpart[bidx] = red[0] + red[1] + red[2] + red[3];
}

// --------------------------------------------------------------------------
// Kernel 4: perplexity from histogram + loss from block partials.
__global__ __launch_bounds__(1024) void finalize_kernel(
    const int* __restrict__ counts,
    const float* __restrict__ bpart,
    float* __restrict__ out)
{
    __shared__ float redp[16], redl[16];
    int tid = threadIdx.x;
    float sp = 0.f;
#pragma unroll
    for (int k = tid; k < KK; k += 1024) {
        float p = (float)counts[k] * (1.0f / (float)NN);
        sp += p * logf(p + 1e-10f);
    }
    float ls = 0.f;
#pragma unroll
    for (int i = tid; i < NQBLK; i += 1024) ls += bpart[i];
#pragma unroll
    for (int off = 32; off > 0; off >>= 1) {
        sp += __shfl_down(sp, off, 64);
        ls += __shfl_down(ls, off, 64);
    }
    if ((tid & 63) == 0) { redp[tid >> 6] = sp; redl[tid >> 6] = ls; }
    __syncthreads();
    if (tid == 0) {
        float tot = 0.f, lsum = 0.f;
#pragma unroll
        for (int i = 0; i < 16; ++i) { tot += redp[i]; lsum += redl[i]; }
        out[OUT_PPL]  = expf(-tot);
        out[OUT_LOSS] = lsum * 1.25f / (float)NUMEL;
    }
}

// --------------------------------------------------------------------------
extern "C" void kernel_launch(void* const* d_in, const int* in_sizes, int n_in,
                              void* d_out, int out_size, void* d_ws, size_t ws_size,
                              hipStream_t stream) {
    const float* x   = (const float*)d_in[0];
    const float* emb = (const float*)d_in[1];
    float* out = (float*)d_out;
    char*  ws  = (char*)d_ws;

    float*  h2p    = (float*)(ws + WS_H2P);
    int*    counts = (int*)(ws + WS_COUNTS);
    ushort* ebf    = (ushort*)(ws + WS_EBF);
    float*  pv     = (float*)(ws + WS_PV);
    ushort* pi     = (ushort*)(ws + WS_PI);
    float*  bpart  = (float*)(ws + WS_BPART);   // aliases h2p (dead after argmin)

    prep_emb<<<128, 256, 0, stream>>>(emb, ebf, h2p, counts);
    argmin_mfma<<<512, 256, 0, stream>>>(x, ebf, h2p, pv, pi);
    quant_kernel<<<NQBLK, 256, 0, stream>>>(x, emb, pv, pi, counts, out, bpart);
    finalize_kernel<<<1, 1024, 0, stream>>>(counts, bpart, out);
}